// Round 7
// baseline (186.953 us; speedup 1.0000x reference)
//
#include <hip/hip_runtime.h>
#include <hip/hip_bf16.h>
#include <math.h>

typedef __bf16 bf16x8 __attribute__((ext_vector_type(8)));
typedef float  f32x4  __attribute__((ext_vector_type(4)));
typedef unsigned short ushort_t;
typedef unsigned char  u8;
typedef unsigned int   u32;

#define N_POI 4096
#define NB    8
#define NPAIR 4
#define NDAYS 4
#define LSEQ  64
#define NROWS 32   // NB*NDAYS
#define NBINS 102  // 101 intervals + 1 pad/clamp slot
#define KC    6    // global K-split factor (32 rb x 6 kc x 4 pairs = 768 blocks)

static __device__ __forceinline__ u32 bf16bits(float f) {
  u32 x = __float_as_uint(f);
  return ((x + 0x7FFFu + ((x >> 16) & 1u)) >> 16) & 0xFFFFu;  // RTNE
}

static __device__ __forceinline__ float lo16f(u32 v) {
  return __uint_as_float(v << 16);
}
static __device__ __forceinline__ float hi16f(u32 v) {
  return __uint_as_float(v & 0xFFFF0000u);
}

// async 16B global -> LDS (linear dest, per-lane source)
static __device__ __forceinline__ void gload16(void* lds, const void* g) {
  __builtin_amdgcn_global_load_lds(
      (const __attribute__((address_space(1))) u32*)g,
      (__attribute__((address_space(3))) u32*)lds, 16, 0, 0);
}

// ---------------------------------------------------------------------------
// K2a (runs FIRST): per-sample setup (argsort of ids, last-day spans,
// bincount/63 weights). Only reads dm/seq/ids.
// ---------------------------------------------------------------------------
__global__ __launch_bounds__(64) void k_sample(const int* __restrict__ ids,
                                               const int* __restrict__ seq,
                                               const float* __restrict__ dm,
                                               float* __restrict__ tfp,
                                               u32* __restrict__ tbu,
                                               int* __restrict__ meta) {
  __shared__ int sh_ids[NROWS];
  __shared__ int sh_order[NROWS];
  __shared__ int sh_cnt[NBINS];
  __shared__ int sh_last[LSEQ];
  __shared__ int sh_nb;
  const int tid = threadIdx.x, s = blockIdx.x;
  if (tid < NROWS) sh_ids[tid] = ids[tid];
  for (int k = tid; k < NBINS; k += 64) sh_cnt[k] = 0;
  if (tid == 0) sh_nb = 0;
  __syncthreads();
  if (tid < NROWS) {
    const int my = sh_ids[tid];
    int rank = 0, first = 1;
    for (int j = 0; j < NROWS; ++j) {
      const int v = sh_ids[j];
      if (v < my || (v == my && j < tid)) rank++;
      if (v == my && j < tid) first = 0;
    }
    sh_order[rank] = tid;
    if (first) atomicAdd(&sh_nb, 1);
  }
  __syncthreads();
  const int nb = sh_nb;
  const int days = NROWS / nb;
  if (s == 0) {
    if (tid < NROWS) meta[tid] = sh_order[tid];
    if (tid == 0) meta[NROWS] = days;
  }
  const int lastRow = sh_order[s * days + days - 1];
  sh_last[tid] = seq[lastRow * LSEQ + tid];
  __syncthreads();
  if (tid < LSEQ - 1) {
    const float v = dm[(size_t)(sh_last[tid] - 1) * N_POI + (sh_last[tid + 1] - 1)];
    int si = (int)ceilf(2.0f * v);
    si = min(max(si, 0), 101);
    atomicAdd(&sh_cnt[si], 1);
  }
  __syncthreads();
  const float inv = 1.0f / (float)(LSEQ - 1);
  for (int k = tid; k < 128; k += 64) {
    const float wv = (k < NBINS) ? (float)sh_cnt[k] * inv : 0.0f;
    tfp[s * 128 + k] = wv;
    tbu[s * 128 + k] = bf16bits(wv);
  }
}

// ---------------------------------------------------------------------------
// K1 (fused): bucketize dm row (side='right' == floor(2v)+1) into uint8,
// build the row histogram in LDS with a PER-WAVE copy (4-way split: removes
// cross-wave same-address atomic serialization; intra-wave collisions over
// 102 bins remain), then FUSE the per-sample rowsum: dot_s = sum_k h[k]*t_s[k],
// diag byte captured in-block, rbuf[s][row] = rsqrt(dot - t_s[bii] + 1).
// ---------------------------------------------------------------------------
__global__ __launch_bounds__(256) void k_bucket(const float* __restrict__ dm,
                                                const float* __restrict__ tfp,
                                                u8* __restrict__ bucket,
                                                float* __restrict__ rbuf) {
  const int row = blockIdx.x, tid = threadIdx.x;
  __shared__ int h[4][NBINS];
  __shared__ float tl[NB][NBINS];
  __shared__ int sh_bii;
  for (int k = tid; k < 4 * NBINS; k += 256) ((int*)h)[k] = 0;
  __syncthreads();
  const float4* drow = (const float4*)(dm + (size_t)row * N_POI);
  u32* brow = (u32*)(bucket + (size_t)row * N_POI);
  int* hp = h[tid >> 6];  // per-wave histogram copy
  const int jdiag = row >> 2;
  for (int it = 0; it < 4; ++it) {
    const int j = it * 256 + tid;
    const float4 v = drow[j];
    const int b0 = min((int)(2.0f * v.x) + 1, 101);
    const int b1 = min((int)(2.0f * v.y) + 1, 101);
    const int b2 = min((int)(2.0f * v.z) + 1, 101);
    const int b3 = min((int)(2.0f * v.w) + 1, 101);
    atomicAdd(&hp[b0], 1); atomicAdd(&hp[b1], 1);
    atomicAdd(&hp[b2], 1); atomicAdd(&hp[b3], 1);
    const u32 pk = (u32)b0 | ((u32)b1 << 8) | ((u32)b2 << 16) | ((u32)b3 << 24);
    if (j == jdiag) sh_bii = (int)((pk >> (8 * (row & 3))) & 255u);
    brow[j] = pk;
  }
  // stage t tables (8 x 102 floats) while histogram finishes
  for (int idx = tid; idx < NB * NBINS; idx += 256)
    tl[idx / NBINS][idx % NBINS] = tfp[(idx / NBINS) * 128 + (idx % NBINS)];
  __syncthreads();
  for (int k = tid; k < NBINS; k += 256)
    h[0][k] += h[1][k] + h[2][k] + h[3][k];
  __syncthreads();
  // 32 lanes per sample: dot_s = sum_k h[k] * t_s[k]
  const int s = tid >> 5, ln = tid & 31;
  float dot = 0.f;
  for (int k = ln; k < NBINS; k += 32) dot += (float)h[0][k] * tl[s][k];
#pragma unroll
  for (int off = 16; off >= 1; off >>= 1) dot += __shfl_down(dot, off, 32);
  if (ln == 0) {
    const float ri = rsqrtf(dot - tl[s][sh_bii] + 1.0f);  // diag W[i,i]=1
    rbuf[s * N_POI + row] = ri;
  }
}

// ---------------------------------------------------------------------------
// K2b (slimmed): Y1^T[d][i] = bf16(r_i * poi_emb[i][d]). float4 poi loads.
// ---------------------------------------------------------------------------
__global__ __launch_bounds__(256) void k_rows(const float* __restrict__ rbuf,
                                              const float* __restrict__ poi,
                                              ushort_t* __restrict__ y1t) {
  const int s = blockIdx.y;
  const int i = blockIdx.x * 256 + threadIdx.x;
  const float ri = rbuf[s * N_POI + i];
  const float4* prow = (const float4*)(poi + (size_t)(i + 1) * 64);
  ushort_t* dst = y1t + (size_t)s * 64 * N_POI + i;
#pragma unroll
  for (int q = 0; q < 16; ++q) {
    const float4 v = prow[q];
    dst[(size_t)(4 * q + 0) * N_POI] = (ushort_t)bf16bits(ri * v.x);
    dst[(size_t)(4 * q + 1) * N_POI] = (ushort_t)bf16bits(ri * v.y);
    dst[(size_t)(4 * q + 2) * N_POI] = (ushort_t)bf16bits(ri * v.z);
    dst[(size_t)(4 * q + 3) * N_POI] = (ushort_t)bf16bits(ri * v.w);
  }
}

// ---------------------------------------------------------------------------
// K3: GCN layer partial GEMM, SAMPLE-PAIR version (proven core, round 6).
// A = t[bucket] gathered ONCE per pair from pair-packed LUT; Y^T staged via
// global_load_lds, double-buffered, ONE vmcnt(0)+barrier per tile (do not
// replace with register prefetch -- compiler sinks it, rounds 1/2/4).
// CHANGE this round: epilogue stores pair-interleaved u32 partials
// (lo=s0, hi=s1): 32 u32 stores (full-line) instead of 64 u16 (half-line).
// Grid (32 rb, KC=6, 4 pairs) = 768 blocks -> 3 blocks/CU, 12 waves/CU.
// ---------------------------------------------------------------------------
__global__ __launch_bounds__(256, 3) void k_layer(
    const u8* __restrict__ bucket, const u32* __restrict__ tbu,
    const ushort_t* __restrict__ yin, u32* __restrict__ part) {
  const int rb = blockIdx.x, kc = blockIdx.y, g = blockIdx.z;
  const int s0 = 2 * g, s1 = 2 * g + 1;
  const int tid = threadIdx.x;
  const int lane = tid & 63, w = tid >> 6;
  const int loff = tid & 31;

  __shared__ u32 trep[NBINS * 32];          // pair-packed LUT (s0 lo | s1 hi)
  __shared__ ushort_t Ybuf[2][2][64 * 64];  // [dbuf][sample], 8KB tiles

  const int gi0 = rb * 128;
  const int r0 = gi0 + w * 32 + (lane & 15);
  const u8* brow0 = bucket + (size_t)r0 * N_POI;
  const u8* brow1 = brow0 + (size_t)16 * N_POI;
  const int kq = (lane >> 4) * 8;

  const ushort_t* ybase0 = yin + (size_t)s0 * 64 * N_POI;
  const ushort_t* ybase1 = yin + (size_t)s1 * 64 * N_POI;

  // staging source (pre-swizzled column): thread covers LDS rows tid>>3 and
  // 32+(tid>>3), 16B at byte (tid&7)*16 of the 128B row, for BOTH samples.
  // perm(r) = (r&7) ^ ((r>>3)&1); LDS(r,b) holds Y(r, b ^ perm(r)<<4).
  const int d0s = tid >> 3, d1s = 32 + d0s;
  const int bly = (tid & 7) * 16;
  const int sw0 = bly ^ (((d0s & 7) ^ ((d0s >> 3) & 1)) << 4);
  const int sw1 = bly ^ (((d1s & 7) ^ ((d1s >> 3) & 1)) << 4);
  const char* g00 = (const char*)(ybase0 + (size_t)d0s * N_POI) + sw0;
  const char* g01 = (const char*)(ybase0 + (size_t)d1s * N_POI) + sw1;
  const char* g10 = (const char*)(ybase1 + (size_t)d0s * N_POI) + sw0;
  const char* g11 = (const char*)(ybase1 + (size_t)d1s * N_POI) + sw1;

  const int kt0 = (kc * 64) / KC, kt1 = ((kc + 1) * 64) / KC;  // 10-11 tiles

  uint2 bpA[4], bpB[4];

#define LOADB_(dst, ktv)                                   \
  {                                                        \
    const int _kb = (ktv) * 64;                            \
    dst[0] = *(const uint2*)(brow0 + _kb + kq);            \
    dst[1] = *(const uint2*)(brow0 + _kb + 32 + kq);       \
    dst[2] = *(const uint2*)(brow1 + _kb + kq);            \
    dst[3] = *(const uint2*)(brow1 + _kb + 32 + kq);       \
  }

#define STAGE_(bufi, ktv)                                  \
  {                                                        \
    const size_t _kb = (size_t)(ktv) * 128;                \
    char* _lb = (char*)&Ybuf[bufi][0][0] + tid * 16;       \
    gload16(_lb, g00 + _kb);                               \
    gload16(_lb + 4096, g01 + _kb);                        \
    gload16(_lb + 8192, g10 + _kb);                        \
    gload16(_lb + 12288, g11 + _kb);                       \
  }

  // prologue: stage first tile + first bucket bytes + pair-packed LUT
  STAGE_(0, kt0);
  LOADB_(bpA, kt0);
  for (int idx = tid; idx < NBINS * 32; idx += 256) {
    const int b = idx >> 5;
    trep[idx] = tbu[s0 * 128 + b] | (tbu[s1 * 128 + b] << 16);
  }

  f32x4 acc0[2][4], acc1[2][4];
#pragma unroll
  for (int mt = 0; mt < 2; ++mt)
#pragma unroll
    for (int nt = 0; nt < 4; ++nt) {
      acc0[mt][nt] = (f32x4){0.f, 0.f, 0.f, 0.f};
      acc1[mt][nt] = (f32x4){0.f, 0.f, 0.f, 0.f};
    }

  asm volatile("s_waitcnt vmcnt(0)" ::: "memory");
  __syncthreads();  // trep + stage(kt0) ready

#define BODY_(CB, PB, CUR)                                                     \
  {                                                                            \
    const int k0 = kt * 64;                                                    \
    if (kt + 1 < kt1) { STAGE_((CUR) ^ 1, kt + 1); LOADB_(PB, kt + 1); }       \
    bf16x8 af0[2][2], af1[2][2];                                               \
    _Pragma("unroll") for (int mt = 0; mt < 2; ++mt) {                         \
      _Pragma("unroll") for (int ks = 0; ks < 2; ++ks) {                       \
        const uint2 bb = CB[mt * 2 + ks];                                      \
        u32 tv[8];                                                             \
        _Pragma("unroll") for (int e = 0; e < 4; ++e) tv[e] =                  \
            trep[((bb.x >> (8 * e)) & 255u) * 32 + loff];                      \
        _Pragma("unroll") for (int e = 0; e < 4; ++e) tv[4 + e] =              \
            trep[((bb.y >> (8 * e)) & 255u) * 32 + loff];                      \
        const u32 de = (u32)(r0 + mt * 16 - (k0 + ks * 32 + kq));              \
        if (de < 8u) { /* diagonal A[i,i] = 1.0 for both samples */            \
          _Pragma("unroll") for (int e = 0; e < 8; ++e)                        \
              if (de == (u32)e) tv[e] = 0x3F803F80u;                           \
        }                                                                      \
        uint4 p0, p1;                                                          \
        p0.x = (tv[0] & 0xFFFFu) | (tv[1] << 16);                              \
        p0.y = (tv[2] & 0xFFFFu) | (tv[3] << 16);                              \
        p0.z = (tv[4] & 0xFFFFu) | (tv[5] << 16);                              \
        p0.w = (tv[6] & 0xFFFFu) | (tv[7] << 16);                              \
        p1.x = (tv[0] >> 16) | (tv[1] & 0xFFFF0000u);                          \
        p1.y = (tv[2] >> 16) | (tv[3] & 0xFFFF0000u);                          \
        p1.z = (tv[4] >> 16) | (tv[5] & 0xFFFF0000u);                          \
        p1.w = (tv[6] >> 16) | (tv[7] & 0xFFFF0000u);                          \
        union { uint4 u; bf16x8 v; } c0, c1;                                   \
        c0.u = p0; c1.u = p1;                                                  \
        af0[mt][ks] = c0.v; af1[mt][ks] = c1.v;                                \
      }                                                                        \
    }                                                                          \
    const char* _y0 = (const char*)&Ybuf[CUR][0][0];                           \
    const char* _y1 = (const char*)&Ybuf[CUR][1][0];                           \
    _Pragma("unroll") for (int ks = 0; ks < 2; ++ks) {                         \
      _Pragma("unroll") for (int nt = 0; nt < 4; ++nt) {                       \
        const int rY = nt * 16 + (lane & 15);                                  \
        const int pm = (rY & 7) ^ ((rY >> 3) & 1);                             \
        const int la = rY * 128 + (((ks * 4 + (lane >> 4)) ^ pm) << 4);        \
        union { uint4 u; bf16x8 v; } b0, b1;                                   \
        b0.u = *(const uint4*)(_y0 + la);                                      \
        b1.u = *(const uint4*)(_y1 + la);                                      \
        acc0[0][nt] = __builtin_amdgcn_mfma_f32_16x16x32_bf16(af0[0][ks], b0.v, \
                                                              acc0[0][nt], 0, 0, 0); \
        acc0[1][nt] = __builtin_amdgcn_mfma_f32_16x16x32_bf16(af0[1][ks], b0.v, \
                                                              acc0[1][nt], 0, 0, 0); \
        acc1[0][nt] = __builtin_amdgcn_mfma_f32_16x16x32_bf16(af1[0][ks], b1.v, \
                                                              acc1[0][nt], 0, 0, 0); \
        acc1[1][nt] = __builtin_amdgcn_mfma_f32_16x16x32_bf16(af1[1][ks], b1.v, \
                                                              acc1[1][nt], 0, 0, 0); \
      }                                                                        \
    }                                                                          \
    asm volatile("s_waitcnt vmcnt(0)" ::: "memory");                           \
    __syncthreads(); /* stage(kt+1) landed; buf[CUR] reads done for all */     \
  }

  int kt = kt0;
  while (true) {
    BODY_(bpA, bpB, 0);
    if (++kt >= kt1) break;
    BODY_(bpB, bpA, 1);
    if (++kt >= kt1) break;
  }

#undef BODY_
#undef STAGE_
#undef LOADB_

  // epilogue: pair-interleaved u32 partials (lo=s0, hi=s1).
  // C/D layout col = lane&15, row = (lane>>4)*4+reg
#pragma unroll
  for (int mt = 0; mt < 2; ++mt) {
#pragma unroll
    for (int e = 0; e < 4; ++e) {
      const int row = gi0 + w * 32 + mt * 16 + (lane >> 4) * 4 + e;
#pragma unroll
      for (int nt = 0; nt < 4; ++nt) {
        const int col = nt * 16 + (lane & 15);
        part[(((size_t)kc * NPAIR + g) * N_POI + row) * 64 + col] =
            bf16bits(acc0[mt][nt][e]) | (bf16bits(acc1[mt][nt][e]) << 16);
      }
    }
  }
}

// ---------------------------------------------------------------------------
// K3b: reduce KC pair-packed partials for LAYER 1, PER-PAIR blocks:
// t = tanh(r*x) for both samples; table = poi_emb + t (fp32);
// y2t^T = bf16(r*t) via LDS transpose. (Layer-2 reduce folded into k_gather.)
// ---------------------------------------------------------------------------
__global__ __launch_bounds__(256) void k_reduce(
    const u32* __restrict__ part, const float* __restrict__ rbuf,
    const float* __restrict__ poi, float* __restrict__ table,
    ushort_t* __restrict__ y2t) {
  const int it = blockIdx.x, g = blockIdx.y, tid = threadIdx.x;
  const int s0 = 2 * g, s1 = 2 * g + 1;
  __shared__ ushort_t Tt[2][64 * 72];
#pragma unroll
  for (int j = 0; j < 2; ++j) {
    const int s2 = tid + j * 256;
    const int iloc = s2 >> 3, d0 = (s2 & 7) * 8;
    const int i = it * 64 + iloc;
    const size_t po = ((size_t)g * N_POI + i) * 64 + d0;  // u32 index in slice
    float x0[8] = {0.f, 0.f, 0.f, 0.f, 0.f, 0.f, 0.f, 0.f};
    float x1[8] = {0.f, 0.f, 0.f, 0.f, 0.f, 0.f, 0.f, 0.f};
#pragma unroll
    for (int c = 0; c < KC; ++c) {
      const u32* sp = part + (size_t)c * NPAIR * N_POI * 64;
      uint4 a = *(const uint4*)(sp + po);
      uint4 b = *(const uint4*)(sp + po + 4);
      const u32* au = (const u32*)&a;
      const u32* bu = (const u32*)&b;
#pragma unroll
      for (int q = 0; q < 4; ++q) {
        x0[q] += lo16f(au[q]);     x1[q] += hi16f(au[q]);
        x0[4 + q] += lo16f(bu[q]); x1[4 + q] += hi16f(bu[q]);
      }
    }
    const float r0 = rbuf[s0 * N_POI + i];
    const float r1 = rbuf[s1 * N_POI + i];
    float t0[8], t1[8];
#pragma unroll
    for (int e = 0; e < 8; ++e) { t0[e] = tanhf(r0 * x0[e]); t1[e] = tanhf(r1 * x1[e]); }
    const float* prow = poi + (size_t)(i + 1) * 64 + d0;
    float4 pz0 = *(const float4*)prow;
    float4 pz1 = *(const float4*)(prow + 4);
    float* trow0 = table + ((size_t)s0 * N_POI + i) * 64 + d0;
    float* trow1 = table + ((size_t)s1 * N_POI + i) * 64 + d0;
    float4 o;
    o = (float4){pz0.x + t0[0], pz0.y + t0[1], pz0.z + t0[2], pz0.w + t0[3]};
    *(float4*)trow0 = o;
    o = (float4){pz1.x + t0[4], pz1.y + t0[5], pz1.z + t0[6], pz1.w + t0[7]};
    *(float4*)(trow0 + 4) = o;
    o = (float4){pz0.x + t1[0], pz0.y + t1[1], pz0.z + t1[2], pz0.w + t1[3]};
    *(float4*)trow1 = o;
    o = (float4){pz1.x + t1[4], pz1.y + t1[5], pz1.z + t1[6], pz1.w + t1[7]};
    *(float4*)(trow1 + 4) = o;
#pragma unroll
    for (int e = 0; e < 8; ++e) {
      Tt[0][(d0 + e) * 72 + iloc] = (ushort_t)bf16bits(r0 * t0[e]);
      Tt[1][(d0 + e) * 72 + iloc] = (ushort_t)bf16bits(r1 * t1[e]);
    }
  }
  __syncthreads();
  const int d = tid >> 2, i0 = (tid & 3) * 16;
#pragma unroll
  for (int ps = 0; ps < 2; ++ps) {
    uint4 a = *(const uint4*)&Tt[ps][d * 72 + i0];
    uint4 b = *(const uint4*)&Tt[ps][d * 72 + i0 + 8];
    ushort_t* dst = y2t + ((size_t)(2 * g + ps) * 64 + d) * N_POI + it * 64 + i0;
    *(uint4*)dst = a;
    *(uint4*)(dst + 8) = b;
  }
}

// ---------------------------------------------------------------------------
// K4: gather + fused layer-2 reduce (pair-packed part):
// out[r][p][:] = (id==0) ? poi[0]*8
//              : (table_L1[s][id-1] + tanh(r * sum_kc part2)) * 8
// ---------------------------------------------------------------------------
__global__ __launch_bounds__(256) void k_gather(const int* __restrict__ seq,
                                                const int* __restrict__ meta,
                                                const float* __restrict__ table,
                                                const float* __restrict__ poi,
                                                const u32* __restrict__ part,
                                                const float* __restrict__ rbuf,
                                                float* __restrict__ out) {
  const int r = blockIdx.x;
  const int p = blockIdx.y * 4 + (threadIdx.x >> 6);
  const int d = threadIdx.x & 63;
  const int days = meta[NROWS];
  const int srcrow = meta[r];
  const int s = r / days;
  const int id = seq[srcrow * LSEQ + p];
  float v;
  if (id == 0) {
    v = poi[d];
  } else {
    const size_t po = (((size_t)(s >> 1)) * N_POI + (id - 1)) * 64 + d;
    float x2 = 0.f;
#pragma unroll
    for (int c = 0; c < KC; ++c) {
      const u32 w = part[(size_t)c * NPAIR * N_POI * 64 + po];
      x2 += (s & 1) ? hi16f(w) : lo16f(w);
    }
    v = table[((size_t)s * N_POI + (id - 1)) * 64 + d] +
        tanhf(rbuf[s * N_POI + (id - 1)] * x2);
  }
  out[((size_t)r * LSEQ + p) * 64 + d] = v * 8.0f;
}

// ---------------------------------------------------------------------------
extern "C" void kernel_launch(void* const* d_in, const int* in_sizes, int n_in,
                              void* d_out, int out_size, void* d_ws, size_t ws_size,
                              hipStream_t stream) {
  (void)in_sizes; (void)n_in; (void)out_size; (void)ws_size;
  const float* poi = (const float*)d_in[0];  // (4097, 64) f32
  const float* dm  = (const float*)d_in[1];  // (4096, 4096) f32
  const int*   seq = (const int*)d_in[2];    // (32, 64) i32
  const int*   ids = (const int*)d_in[3];    // (32,) i32
  // d_in[4]: GCN_layer_num (== 2 per setup_inputs)

  char* ws = (char*)d_ws;
  size_t off = 0;
  auto carve = [&](size_t bytes) {
    char* p = ws + off;
    off += (bytes + 255) & ~(size_t)255;
    return p;
  };
  u8*       bucket = (u8*)carve((size_t)N_POI * N_POI);            // 16.78 MB
  float*    tfp    = (float*)carve((size_t)NB * 128 * 4);
  u32*      tbu    = (u32*)carve((size_t)NB * 128 * 4);
  float*    rbuf   = (float*)carve((size_t)NB * N_POI * 4);
  // table (fp32, 8.39MB) aliases y1t (bf16, 4.19MB): y1t dead after k_layer L1;
  // table first written by k_reduce L1 (later in stream). y2t kept separate.
  float*    table  = (float*)carve((size_t)NB * N_POI * 64 * 4);     // 8.39 MB
  ushort_t* y1t    = (ushort_t*)table;
  ushort_t* y2t    = (ushort_t*)carve((size_t)NB * 64 * N_POI * 2);  // 4.19 MB
  u32*      part   = (u32*)carve((size_t)KC * NPAIR * N_POI * 64 * 4);  // 25.2 MB
  int*      meta   = (int*)carve(256);

  k_sample<<<NB, 64, 0, stream>>>(ids, seq, dm, tfp, tbu, meta);
  k_bucket<<<N_POI, 256, 0, stream>>>(dm, tfp, bucket, rbuf);
  k_rows<<<dim3(16, NB), 256, 0, stream>>>(rbuf, poi, y1t);
  k_layer<<<dim3(32, KC, NPAIR), 256, 0, stream>>>(bucket, tbu, y1t, part);
  k_reduce<<<dim3(64, NPAIR), 256, 0, stream>>>(part, rbuf, poi, table, y2t);
  k_layer<<<dim3(32, KC, NPAIR), 256, 0, stream>>>(bucket, tbu, y2t, part);
  k_gather<<<dim3(NROWS, 16), 256, 0, stream>>>(seq, meta, table, poi, part, rbuf,
                                                (float*)d_out);
}

// Round 8
// 167.180 us; speedup vs baseline: 1.1183x; 1.1183x over previous
//
#include <hip/hip_runtime.h>
#include <hip/hip_bf16.h>
#include <math.h>

typedef __bf16 bf16x8 __attribute__((ext_vector_type(8)));
typedef float  f32x4  __attribute__((ext_vector_type(4)));
typedef unsigned short ushort_t;
typedef unsigned char  u8;
typedef unsigned int   u32;

#define N_POI 4096
#define NB    8
#define NPAIR 4
#define NDAYS 4
#define LSEQ  64
#define NROWS 32   // NB*NDAYS
#define NBINS 102  // 101 intervals + 1 pad/clamp slot
#define KC    6    // L1 K-split (32 rb x 6 kc x 4 pairs = 768 blocks)
#define KC2   16   // L2 K-split (16 pos-blocks x 16 kc = 256 blocks)
#define NPOS  2048 // NROWS * LSEQ gathered positions

static __device__ __forceinline__ u32 bf16bits(float f) {
  u32 x = __float_as_uint(f);
  return ((x + 0x7FFFu + ((x >> 16) & 1u)) >> 16) & 0xFFFFu;  // RTNE
}

static __device__ __forceinline__ float lo16f(u32 v) {
  return __uint_as_float(v << 16);
}
static __device__ __forceinline__ float hi16f(u32 v) {
  return __uint_as_float(v & 0xFFFF0000u);
}

// async 16B global -> LDS (linear dest, per-lane source)
static __device__ __forceinline__ void gload16(void* lds, const void* g) {
  __builtin_amdgcn_global_load_lds(
      (const __attribute__((address_space(1))) u32*)g,
      (__attribute__((address_space(3))) u32*)lds, 16, 0, 0);
}

// ---------------------------------------------------------------------------
// K2a (runs FIRST): per-sample setup (argsort of ids, last-day spans,
// bincount/63 weights) + rowids table for the sparse-output layer-2 GEMM:
// rowids[r*64+p] = seq[order[r]][p]-1 (clamped to 0).
// ---------------------------------------------------------------------------
__global__ __launch_bounds__(64) void k_sample(const int* __restrict__ ids,
                                               const int* __restrict__ seq,
                                               const float* __restrict__ dm,
                                               float* __restrict__ tfp,
                                               u32* __restrict__ tbu,
                                               int* __restrict__ meta,
                                               int* __restrict__ rowids) {
  __shared__ int sh_ids[NROWS];
  __shared__ int sh_order[NROWS];
  __shared__ int sh_cnt[NBINS];
  __shared__ int sh_last[LSEQ];
  __shared__ int sh_nb;
  const int tid = threadIdx.x, s = blockIdx.x;
  if (tid < NROWS) sh_ids[tid] = ids[tid];
  for (int k = tid; k < NBINS; k += 64) sh_cnt[k] = 0;
  if (tid == 0) sh_nb = 0;
  __syncthreads();
  if (tid < NROWS) {
    const int my = sh_ids[tid];
    int rank = 0, first = 1;
    for (int j = 0; j < NROWS; ++j) {
      const int v = sh_ids[j];
      if (v < my || (v == my && j < tid)) rank++;
      if (v == my && j < tid) first = 0;
    }
    sh_order[rank] = tid;
    if (first) atomicAdd(&sh_nb, 1);
  }
  __syncthreads();
  const int nb = sh_nb;
  const int days = NROWS / nb;
  if (s == 0) {
    if (tid < NROWS) meta[tid] = sh_order[tid];
    if (tid == 0) meta[NROWS] = days;
  }
  // rowids for this sample's output rows (positions consumed by k_layer2)
  for (int day = 0; day < days; ++day) {
    const int r = s * days + day;
    const int src = sh_order[r];
    rowids[r * LSEQ + tid] = max(seq[src * LSEQ + tid] - 1, 0);
  }
  const int lastRow = sh_order[s * days + days - 1];
  sh_last[tid] = seq[lastRow * LSEQ + tid];
  __syncthreads();
  if (tid < LSEQ - 1) {
    const float v = dm[(size_t)(sh_last[tid] - 1) * N_POI + (sh_last[tid + 1] - 1)];
    int si = (int)ceilf(2.0f * v);
    si = min(max(si, 0), 101);
    atomicAdd(&sh_cnt[si], 1);
  }
  __syncthreads();
  const float inv = 1.0f / (float)(LSEQ - 1);
  for (int k = tid; k < 128; k += 64) {
    const float wv = (k < NBINS) ? (float)sh_cnt[k] * inv : 0.0f;
    tfp[s * 128 + k] = wv;
    tbu[s * 128 + k] = bf16bits(wv);
  }
}

// ---------------------------------------------------------------------------
// K1 (fused): bucketize dm row into uint8 + per-wave LDS histogram, then
// fused per-sample rowsum: rbuf[s][row] = rsqrt(dot - t_s[bii] + 1).
// ---------------------------------------------------------------------------
__global__ __launch_bounds__(256) void k_bucket(const float* __restrict__ dm,
                                                const float* __restrict__ tfp,
                                                u8* __restrict__ bucket,
                                                float* __restrict__ rbuf) {
  const int row = blockIdx.x, tid = threadIdx.x;
  __shared__ int h[4][NBINS];
  __shared__ float tl[NB][NBINS];
  __shared__ int sh_bii;
  for (int k = tid; k < 4 * NBINS; k += 256) ((int*)h)[k] = 0;
  __syncthreads();
  const float4* drow = (const float4*)(dm + (size_t)row * N_POI);
  u32* brow = (u32*)(bucket + (size_t)row * N_POI);
  int* hp = h[tid >> 6];  // per-wave histogram copy
  const int jdiag = row >> 2;
  for (int it = 0; it < 4; ++it) {
    const int j = it * 256 + tid;
    const float4 v = drow[j];
    const int b0 = min((int)(2.0f * v.x) + 1, 101);
    const int b1 = min((int)(2.0f * v.y) + 1, 101);
    const int b2 = min((int)(2.0f * v.z) + 1, 101);
    const int b3 = min((int)(2.0f * v.w) + 1, 101);
    atomicAdd(&hp[b0], 1); atomicAdd(&hp[b1], 1);
    atomicAdd(&hp[b2], 1); atomicAdd(&hp[b3], 1);
    const u32 pk = (u32)b0 | ((u32)b1 << 8) | ((u32)b2 << 16) | ((u32)b3 << 24);
    if (j == jdiag) sh_bii = (int)((pk >> (8 * (row & 3))) & 255u);
    brow[j] = pk;
  }
  for (int idx = tid; idx < NB * NBINS; idx += 256)
    tl[idx / NBINS][idx % NBINS] = tfp[(idx / NBINS) * 128 + (idx % NBINS)];
  __syncthreads();
  for (int k = tid; k < NBINS; k += 256)
    h[0][k] += h[1][k] + h[2][k] + h[3][k];
  __syncthreads();
  const int s = tid >> 5, ln = tid & 31;
  float dot = 0.f;
  for (int k = ln; k < NBINS; k += 32) dot += (float)h[0][k] * tl[s][k];
#pragma unroll
  for (int off = 16; off >= 1; off >>= 1) dot += __shfl_down(dot, off, 32);
  if (ln == 0) {
    const float ri = rsqrtf(dot - tl[s][sh_bii] + 1.0f);  // diag W[i,i]=1
    rbuf[s * N_POI + row] = ri;
  }
}

// ---------------------------------------------------------------------------
// K2b: Y1^T[d][i] = bf16(r_i * poi_emb[i][d]). float4 poi loads.
// ---------------------------------------------------------------------------
__global__ __launch_bounds__(256) void k_rows(const float* __restrict__ rbuf,
                                              const float* __restrict__ poi,
                                              ushort_t* __restrict__ y1t) {
  const int s = blockIdx.y;
  const int i = blockIdx.x * 256 + threadIdx.x;
  const float ri = rbuf[s * N_POI + i];
  const float4* prow = (const float4*)(poi + (size_t)(i + 1) * 64);
  ushort_t* dst = y1t + (size_t)s * 64 * N_POI + i;
#pragma unroll
  for (int q = 0; q < 16; ++q) {
    const float4 v = prow[q];
    dst[(size_t)(4 * q + 0) * N_POI] = (ushort_t)bf16bits(ri * v.x);
    dst[(size_t)(4 * q + 1) * N_POI] = (ushort_t)bf16bits(ri * v.y);
    dst[(size_t)(4 * q + 2) * N_POI] = (ushort_t)bf16bits(ri * v.z);
    dst[(size_t)(4 * q + 3) * N_POI] = (ushort_t)bf16bits(ri * v.w);
  }
}

// ---------------------------------------------------------------------------
// K3: LAYER-1 GCN partial GEMM, sample-pair version (proven, round 6).
// Pair-packed trep LUT, Y^T staged via global_load_lds, double-buffered,
// ONE vmcnt(0)+barrier per tile. Pair-interleaved u32 partials out.
// Grid (32 rb, KC=6, 4 pairs) = 768 blocks -> 3 blocks/CU.
// ---------------------------------------------------------------------------
__global__ __launch_bounds__(256, 3) void k_layer(
    const u8* __restrict__ bucket, const u32* __restrict__ tbu,
    const ushort_t* __restrict__ yin, u32* __restrict__ part) {
  const int rb = blockIdx.x, kc = blockIdx.y, g = blockIdx.z;
  const int s0 = 2 * g, s1 = 2 * g + 1;
  const int tid = threadIdx.x;
  const int lane = tid & 63, w = tid >> 6;
  const int loff = tid & 31;

  __shared__ u32 trep[NBINS * 32];          // pair-packed LUT (s0 lo | s1 hi)
  __shared__ ushort_t Ybuf[2][2][64 * 64];  // [dbuf][sample], 8KB tiles

  const int gi0 = rb * 128;
  const int r0 = gi0 + w * 32 + (lane & 15);
  const u8* brow0 = bucket + (size_t)r0 * N_POI;
  const u8* brow1 = brow0 + (size_t)16 * N_POI;
  const int kq = (lane >> 4) * 8;

  const ushort_t* ybase0 = yin + (size_t)s0 * 64 * N_POI;
  const ushort_t* ybase1 = yin + (size_t)s1 * 64 * N_POI;

  // pre-swizzled staging source: perm(r) = (r&7) ^ ((r>>3)&1)
  const int d0s = tid >> 3, d1s = 32 + d0s;
  const int bly = (tid & 7) * 16;
  const int sw0 = bly ^ (((d0s & 7) ^ ((d0s >> 3) & 1)) << 4);
  const int sw1 = bly ^ (((d1s & 7) ^ ((d1s >> 3) & 1)) << 4);
  const char* g00 = (const char*)(ybase0 + (size_t)d0s * N_POI) + sw0;
  const char* g01 = (const char*)(ybase0 + (size_t)d1s * N_POI) + sw1;
  const char* g10 = (const char*)(ybase1 + (size_t)d0s * N_POI) + sw0;
  const char* g11 = (const char*)(ybase1 + (size_t)d1s * N_POI) + sw1;

  const int kt0 = (kc * 64) / KC, kt1 = ((kc + 1) * 64) / KC;  // 10-11 tiles

  uint2 bpA[4], bpB[4];

#define LOADB_(dst, ktv)                                   \
  {                                                        \
    const int _kb = (ktv) * 64;                            \
    dst[0] = *(const uint2*)(brow0 + _kb + kq);            \
    dst[1] = *(const uint2*)(brow0 + _kb + 32 + kq);       \
    dst[2] = *(const uint2*)(brow1 + _kb + kq);            \
    dst[3] = *(const uint2*)(brow1 + _kb + 32 + kq);       \
  }

#define STAGE_(bufi, ktv)                                  \
  {                                                        \
    const size_t _kb = (size_t)(ktv) * 128;                \
    char* _lb = (char*)&Ybuf[bufi][0][0] + tid * 16;       \
    gload16(_lb, g00 + _kb);                               \
    gload16(_lb + 4096, g01 + _kb);                        \
    gload16(_lb + 8192, g10 + _kb);                        \
    gload16(_lb + 12288, g11 + _kb);                       \
  }

  STAGE_(0, kt0);
  LOADB_(bpA, kt0);
  for (int idx = tid; idx < NBINS * 32; idx += 256) {
    const int b = idx >> 5;
    trep[idx] = tbu[s0 * 128 + b] | (tbu[s1 * 128 + b] << 16);
  }

  f32x4 acc0[2][4], acc1[2][4];
#pragma unroll
  for (int mt = 0; mt < 2; ++mt)
#pragma unroll
    for (int nt = 0; nt < 4; ++nt) {
      acc0[mt][nt] = (f32x4){0.f, 0.f, 0.f, 0.f};
      acc1[mt][nt] = (f32x4){0.f, 0.f, 0.f, 0.f};
    }

  asm volatile("s_waitcnt vmcnt(0)" ::: "memory");
  __syncthreads();  // trep + stage(kt0) ready

#define BODY_(CB, PB, CUR)                                                     \
  {                                                                            \
    const int k0 = kt * 64;                                                    \
    if (kt + 1 < kt1) { STAGE_((CUR) ^ 1, kt + 1); LOADB_(PB, kt + 1); }       \
    bf16x8 af0[2][2], af1[2][2];                                               \
    _Pragma("unroll") for (int mt = 0; mt < 2; ++mt) {                         \
      _Pragma("unroll") for (int ks = 0; ks < 2; ++ks) {                       \
        const uint2 bb = CB[mt * 2 + ks];                                      \
        u32 tv[8];                                                             \
        _Pragma("unroll") for (int e = 0; e < 4; ++e) tv[e] =                  \
            trep[((bb.x >> (8 * e)) & 255u) * 32 + loff];                      \
        _Pragma("unroll") for (int e = 0; e < 4; ++e) tv[4 + e] =              \
            trep[((bb.y >> (8 * e)) & 255u) * 32 + loff];                      \
        const u32 de = (u32)(r0 + mt * 16 - (k0 + ks * 32 + kq));              \
        if (de < 8u) { /* diagonal A[i,i] = 1.0 for both samples */            \
          _Pragma("unroll") for (int e = 0; e < 8; ++e)                        \
              if (de == (u32)e) tv[e] = 0x3F803F80u;                           \
        }                                                                      \
        uint4 p0, p1;                                                          \
        p0.x = (tv[0] & 0xFFFFu) | (tv[1] << 16);                              \
        p0.y = (tv[2] & 0xFFFFu) | (tv[3] << 16);                              \
        p0.z = (tv[4] & 0xFFFFu) | (tv[5] << 16);                              \
        p0.w = (tv[6] & 0xFFFFu) | (tv[7] << 16);                              \
        p1.x = (tv[0] >> 16) | (tv[1] & 0xFFFF0000u);                          \
        p1.y = (tv[2] >> 16) | (tv[3] & 0xFFFF0000u);                          \
        p1.z = (tv[4] >> 16) | (tv[5] & 0xFFFF0000u);                          \
        p1.w = (tv[6] >> 16) | (tv[7] & 0xFFFF0000u);                          \
        union { uint4 u; bf16x8 v; } c0, c1;                                   \
        c0.u = p0; c1.u = p1;                                                  \
        af0[mt][ks] = c0.v; af1[mt][ks] = c1.v;                                \
      }                                                                        \
    }                                                                          \
    const char* _y0 = (const char*)&Ybuf[CUR][0][0];                           \
    const char* _y1 = (const char*)&Ybuf[CUR][1][0];                           \
    _Pragma("unroll") for (int ks = 0; ks < 2; ++ks) {                         \
      _Pragma("unroll") for (int nt = 0; nt < 4; ++nt) {                       \
        const int rY = nt * 16 + (lane & 15);                                  \
        const int pm = (rY & 7) ^ ((rY >> 3) & 1);                             \
        const int la = rY * 128 + (((ks * 4 + (lane >> 4)) ^ pm) << 4);        \
        union { uint4 u; bf16x8 v; } b0, b1;                                   \
        b0.u = *(const uint4*)(_y0 + la);                                      \
        b1.u = *(const uint4*)(_y1 + la);                                      \
        acc0[0][nt] = __builtin_amdgcn_mfma_f32_16x16x32_bf16(af0[0][ks], b0.v, \
                                                              acc0[0][nt], 0, 0, 0); \
        acc0[1][nt] = __builtin_amdgcn_mfma_f32_16x16x32_bf16(af0[1][ks], b0.v, \
                                                              acc0[1][nt], 0, 0, 0); \
        acc1[0][nt] = __builtin_amdgcn_mfma_f32_16x16x32_bf16(af1[0][ks], b1.v, \
                                                              acc1[0][nt], 0, 0, 0); \
        acc1[1][nt] = __builtin_amdgcn_mfma_f32_16x16x32_bf16(af1[1][ks], b1.v, \
                                                              acc1[1][nt], 0, 0, 0); \
      }                                                                        \
    }                                                                          \
    asm volatile("s_waitcnt vmcnt(0)" ::: "memory");                           \
    __syncthreads(); /* stage(kt+1) landed; buf[CUR] reads done for all */     \
  }

  int kt = kt0;
  while (true) {
    BODY_(bpA, bpB, 0);
    if (++kt >= kt1) break;
    BODY_(bpB, bpA, 1);
    if (++kt >= kt1) break;
  }

#undef BODY_
#undef STAGE_
#undef LOADB_

  // epilogue: pair-interleaved u32 partials (lo=s0, hi=s1).
#pragma unroll
  for (int mt = 0; mt < 2; ++mt) {
#pragma unroll
    for (int e = 0; e < 4; ++e) {
      const int row = gi0 + w * 32 + mt * 16 + (lane >> 4) * 4 + e;
#pragma unroll
      for (int nt = 0; nt < 4; ++nt) {
        const int col = nt * 16 + (lane & 15);
        part[(((size_t)kc * NPAIR + g) * N_POI + row) * 64 + col] =
            bf16bits(acc0[mt][nt][e]) | (bf16bits(acc1[mt][nt][e]) << 16);
      }
    }
  }
}

// ---------------------------------------------------------------------------
// K3b: reduce KC pair-packed partials for LAYER 1: t = tanh(r*x),
// table = poi_emb + t (fp32); y2t^T = bf16(r*t) via LDS transpose.
// ---------------------------------------------------------------------------
__global__ __launch_bounds__(256) void k_reduce(
    const u32* __restrict__ part, const float* __restrict__ rbuf,
    const float* __restrict__ poi, float* __restrict__ table,
    ushort_t* __restrict__ y2t) {
  const int it = blockIdx.x, g = blockIdx.y, tid = threadIdx.x;
  const int s0 = 2 * g, s1 = 2 * g + 1;
  __shared__ ushort_t Tt[2][64 * 72];
#pragma unroll
  for (int j = 0; j < 2; ++j) {
    const int s2 = tid + j * 256;
    const int iloc = s2 >> 3, d0 = (s2 & 7) * 8;
    const int i = it * 64 + iloc;
    const size_t po = ((size_t)g * N_POI + i) * 64 + d0;  // u32 index in slice
    float x0[8] = {0.f, 0.f, 0.f, 0.f, 0.f, 0.f, 0.f, 0.f};
    float x1[8] = {0.f, 0.f, 0.f, 0.f, 0.f, 0.f, 0.f, 0.f};
#pragma unroll
    for (int c = 0; c < KC; ++c) {
      const u32* sp = part + (size_t)c * NPAIR * N_POI * 64;
      uint4 a = *(const uint4*)(sp + po);
      uint4 b = *(const uint4*)(sp + po + 4);
      const u32* au = (const u32*)&a;
      const u32* bu = (const u32*)&b;
#pragma unroll
      for (int q = 0; q < 4; ++q) {
        x0[q] += lo16f(au[q]);     x1[q] += hi16f(au[q]);
        x0[4 + q] += lo16f(bu[q]); x1[4 + q] += hi16f(bu[q]);
      }
    }
    const float r0 = rbuf[s0 * N_POI + i];
    const float r1 = rbuf[s1 * N_POI + i];
    float t0[8], t1[8];
#pragma unroll
    for (int e = 0; e < 8; ++e) { t0[e] = tanhf(r0 * x0[e]); t1[e] = tanhf(r1 * x1[e]); }
    const float* prow = poi + (size_t)(i + 1) * 64 + d0;
    float4 pz0 = *(const float4*)prow;
    float4 pz1 = *(const float4*)(prow + 4);
    float* trow0 = table + ((size_t)s0 * N_POI + i) * 64 + d0;
    float* trow1 = table + ((size_t)s1 * N_POI + i) * 64 + d0;
    float4 o;
    o = (float4){pz0.x + t0[0], pz0.y + t0[1], pz0.z + t0[2], pz0.w + t0[3]};
    *(float4*)trow0 = o;
    o = (float4){pz1.x + t0[4], pz1.y + t0[5], pz1.z + t0[6], pz1.w + t0[7]};
    *(float4*)(trow0 + 4) = o;
    o = (float4){pz0.x + t1[0], pz0.y + t1[1], pz0.z + t1[2], pz0.w + t1[3]};
    *(float4*)trow1 = o;
    o = (float4){pz1.x + t1[4], pz1.y + t1[5], pz1.z + t1[6], pz1.w + t1[7]};
    *(float4*)(trow1 + 4) = o;
#pragma unroll
    for (int e = 0; e < 8; ++e) {
      Tt[0][(d0 + e) * 72 + iloc] = (ushort_t)bf16bits(r0 * t0[e]);
      Tt[1][(d0 + e) * 72 + iloc] = (ushort_t)bf16bits(r1 * t1[e]);
    }
  }
  __syncthreads();
  const int d = tid >> 2, i0 = (tid & 3) * 16;
#pragma unroll
  for (int ps = 0; ps < 2; ++ps) {
    uint4 a = *(const uint4*)&Tt[ps][d * 72 + i0];
    uint4 b = *(const uint4*)&Tt[ps][d * 72 + i0 + 8];
    ushort_t* dst = y2t + ((size_t)(2 * g + ps) * 64 + d) * N_POI + it * 64 + i0;
    *(uint4*)dst = a;
    *(uint4*)(dst + 8) = b;
  }
}

// ---------------------------------------------------------------------------
// K3c: LAYER-2 GCN GEMM, SPARSE OUTPUT. M-space = the 2048 (r,p) seq
// positions (dups recomputed; no inverse map). A-row for position q is
// bucket[rowids[q]][:]; diagonal test uses the actual row id. Single-sample
// trep LUT; Y^T = y2t staged via global_load_lds (round-3 proven core,
// vmcnt(0)+barrier pinned double-buffer). f32 partials (better accuracy
// than the old KC=6 bf16 path). Grid (16 pos-blocks, KC2=16) = 256 blocks,
// 4 K-tiles each -> ~1/16 of the dense L1 work.
// ---------------------------------------------------------------------------
__global__ __launch_bounds__(256) void k_layer2(
    const u8* __restrict__ bucket, const u32* __restrict__ tbu,
    const ushort_t* __restrict__ yin, const int* __restrict__ rowids,
    float* __restrict__ part2) {
  const int rb = blockIdx.x, kc = blockIdx.y;
  const int s = rb >> 1;  // 256 positions per sample (days=4 x 64)
  const int tid = threadIdx.x;
  const int lane = tid & 63, w = tid >> 6;
  const int loff = tid & 31;

  __shared__ u32 trep[NBINS * 32];       // single-sample LUT, 13 KB
  __shared__ ushort_t Ybuf[2][64 * 64];  // 2 x 8 KB Y^T tiles

  const int pos0 = rb * 128 + w * 32 + (lane & 15);
  const int rid0 = rowids[pos0];
  const int rid1 = rowids[pos0 + 16];
  const u8* brow0 = bucket + (size_t)rid0 * N_POI;
  const u8* brow1 = bucket + (size_t)rid1 * N_POI;
  const int kq = (lane >> 4) * 8;

  const ushort_t* ybase = yin + (size_t)s * 64 * N_POI;
  // pre-swizzled staging source: perm(r) = (r&7) ^ ((r>>3)&1)
  const int d0s = tid >> 3, d1s = 32 + d0s;
  const int bly = (tid & 7) * 16;
  const int sw0 = bly ^ (((d0s & 7) ^ ((d0s >> 3) & 1)) << 4);
  const int sw1 = bly ^ (((d1s & 7) ^ ((d1s >> 3) & 1)) << 4);
  const char* gsrc0 = (const char*)(ybase + (size_t)d0s * N_POI) + sw0;
  const char* gsrc1 = (const char*)(ybase + (size_t)d1s * N_POI) + sw1;

  const int kt0 = kc * 4, kt1 = kt0 + 4;

  uint2 bpA[4], bpB[4];

#define LOADB_(dst, ktv)                                   \
  {                                                        \
    const int _kb = (ktv) * 64;                            \
    dst[0] = *(const uint2*)(brow0 + _kb + kq);            \
    dst[1] = *(const uint2*)(brow0 + _kb + 32 + kq);       \
    dst[2] = *(const uint2*)(brow1 + _kb + kq);            \
    dst[3] = *(const uint2*)(brow1 + _kb + 32 + kq);       \
  }

#define STAGE_(bufi, ktv)                                  \
  {                                                        \
    const size_t _kb = (size_t)(ktv) * 128;                \
    char* _lb = (char*)&Ybuf[bufi][0] + tid * 16;          \
    gload16(_lb, gsrc0 + _kb);                             \
    gload16(_lb + 4096, gsrc1 + _kb);                      \
  }

  STAGE_(0, kt0);
  LOADB_(bpA, kt0);
  for (int idx = tid; idx < NBINS * 32; idx += 256)
    trep[idx] = tbu[s * 128 + (idx >> 5)];

  f32x4 acc[2][4];
#pragma unroll
  for (int mt = 0; mt < 2; ++mt)
#pragma unroll
    for (int nt = 0; nt < 4; ++nt) acc[mt][nt] = (f32x4){0.f, 0.f, 0.f, 0.f};

  asm volatile("s_waitcnt vmcnt(0)" ::: "memory");
  __syncthreads();

#define BODY_(CB, PB, CUR)                                                     \
  {                                                                            \
    const int k0 = kt * 64;                                                    \
    if (kt + 1 < kt1) { STAGE_((CUR) ^ 1, kt + 1); LOADB_(PB, kt + 1); }       \
    bf16x8 afr[2][2];                                                          \
    _Pragma("unroll") for (int mt = 0; mt < 2; ++mt) {                         \
      _Pragma("unroll") for (int ks = 0; ks < 2; ++ks) {                       \
        const uint2 bb = CB[mt * 2 + ks];                                      \
        u32 tv[8];                                                             \
        _Pragma("unroll") for (int e = 0; e < 4; ++e) tv[e] =                  \
            trep[((bb.x >> (8 * e)) & 255u) * 32 + loff];                      \
        _Pragma("unroll") for (int e = 0; e < 4; ++e) tv[4 + e] =              \
            trep[((bb.y >> (8 * e)) & 255u) * 32 + loff];                      \
        const int grow = mt ? rid1 : rid0;                                     \
        const u32 de = (u32)(grow - (k0 + ks * 32 + kq));                      \
        if (de < 8u) { /* diagonal A[i,i] = 1.0 */                             \
          _Pragma("unroll") for (int e = 0; e < 8; ++e)                        \
              if (de == (u32)e) tv[e] = 0x3F80u;                               \
        }                                                                      \
        uint4 pk;                                                              \
        pk.x = tv[0] | (tv[1] << 16);                                          \
        pk.y = tv[2] | (tv[3] << 16);                                          \
        pk.z = tv[4] | (tv[5] << 16);                                          \
        pk.w = tv[6] | (tv[7] << 16);                                          \
        union { uint4 u; bf16x8 v; } cvt;                                      \
        cvt.u = pk;                                                            \
        afr[mt][ks] = cvt.v;                                                   \
      }                                                                        \
    }                                                                          \
    const char* _yb = (const char*)&Ybuf[CUR][0];                              \
    _Pragma("unroll") for (int ks = 0; ks < 2; ++ks) {                         \
      _Pragma("unroll") for (int nt = 0; nt < 4; ++nt) {                       \
        const int rY = nt * 16 + (lane & 15);                                  \
        const int pm = (rY & 7) ^ ((rY >> 3) & 1);                             \
        const int la = rY * 128 + (((ks * 4 + (lane >> 4)) ^ pm) << 4);        \
        union { uint4 u; bf16x8 v; } bu;                                       \
        bu.u = *(const uint4*)(_yb + la);                                      \
        acc[0][nt] = __builtin_amdgcn_mfma_f32_16x16x32_bf16(afr[0][ks], bu.v, \
                                                             acc[0][nt], 0, 0, 0); \
        acc[1][nt] = __builtin_amdgcn_mfma_f32_16x16x32_bf16(afr[1][ks], bu.v, \
                                                             acc[1][nt], 0, 0, 0); \
      }                                                                        \
    }                                                                          \
    asm volatile("s_waitcnt vmcnt(0)" ::: "memory");                           \
    __syncthreads();                                                           \
  }

  int kt = kt0;
  while (true) {
    BODY_(bpA, bpB, 0);
    if (++kt >= kt1) break;
    BODY_(bpB, bpA, 1);
    if (++kt >= kt1) break;
  }

#undef BODY_
#undef STAGE_
#undef LOADB_

  // epilogue: f32 partials indexed by position. col = lane&15, row-reg map.
#pragma unroll
  for (int mt = 0; mt < 2; ++mt) {
#pragma unroll
    for (int e = 0; e < 4; ++e) {
      const int pos = rb * 128 + w * 32 + mt * 16 + (lane >> 4) * 4 + e;
#pragma unroll
      for (int nt = 0; nt < 4; ++nt) {
        const int col = nt * 16 + (lane & 15);
        part2[((size_t)kc * NPOS + pos) * 64 + col] = acc[mt][nt][e];
      }
    }
  }
}

// ---------------------------------------------------------------------------
// K4: gather + layer-2 finish:
// out[r][p][:] = (id==0) ? poi[0]*8
//              : (table_L1[s][id-1] + tanh(r_i * sum_kc part2[kc][r*64+p])) * 8
// ---------------------------------------------------------------------------
__global__ __launch_bounds__(256) void k_gather(const int* __restrict__ seq,
                                                const int* __restrict__ meta,
                                                const float* __restrict__ table,
                                                const float* __restrict__ poi,
                                                const float* __restrict__ part2,
                                                const float* __restrict__ rbuf,
                                                float* __restrict__ out) {
  const int r = blockIdx.x;
  const int p = blockIdx.y * 4 + (threadIdx.x >> 6);
  const int d = threadIdx.x & 63;
  const int days = meta[NROWS];
  const int srcrow = meta[r];
  const int s = r / days;
  const int id = seq[srcrow * LSEQ + p];
  float v;
  if (id == 0) {
    v = poi[d];
  } else {
    const size_t gq = (size_t)r * LSEQ + p;
    float x2 = 0.f;
#pragma unroll
    for (int c = 0; c < KC2; ++c)
      x2 += part2[((size_t)c * NPOS + gq) * 64 + d];
    v = table[((size_t)s * N_POI + (id - 1)) * 64 + d] +
        tanhf(rbuf[s * N_POI + (id - 1)] * x2);
  }
  out[((size_t)r * LSEQ + p) * 64 + d] = v * 8.0f;
}

// ---------------------------------------------------------------------------
extern "C" void kernel_launch(void* const* d_in, const int* in_sizes, int n_in,
                              void* d_out, int out_size, void* d_ws, size_t ws_size,
                              hipStream_t stream) {
  (void)in_sizes; (void)n_in; (void)out_size; (void)ws_size;
  const float* poi = (const float*)d_in[0];  // (4097, 64) f32
  const float* dm  = (const float*)d_in[1];  // (4096, 4096) f32
  const int*   seq = (const int*)d_in[2];    // (32, 64) i32
  const int*   ids = (const int*)d_in[3];    // (32,) i32
  // d_in[4]: GCN_layer_num (== 2 per setup_inputs)

  char* ws = (char*)d_ws;
  size_t off = 0;
  auto carve = [&](size_t bytes) {
    char* p = ws + off;
    off += (bytes + 255) & ~(size_t)255;
    return p;
  };
  u8*       bucket = (u8*)carve((size_t)N_POI * N_POI);            // 16.78 MB
  float*    tfp    = (float*)carve((size_t)NB * 128 * 4);
  u32*      tbu    = (u32*)carve((size_t)NB * 128 * 4);
  float*    rbuf   = (float*)carve((size_t)NB * N_POI * 4);
  // table (fp32, 8.39MB) aliases y1t (bf16, 4.19MB): y1t dead after k_layer L1;
  // table first written by k_reduce (later in stream). y2t kept separate.
  float*    table  = (float*)carve((size_t)NB * N_POI * 64 * 4);     // 8.39 MB
  ushort_t* y1t    = (ushort_t*)table;
  ushort_t* y2t    = (ushort_t*)carve((size_t)NB * 64 * N_POI * 2);  // 4.19 MB
  u32*      part   = (u32*)carve((size_t)KC * NPAIR * N_POI * 64 * 4);   // 25.2 MB
  float*    part2  = (float*)carve((size_t)KC2 * NPOS * 64 * 4);         // 8.39 MB
  int*      rowids = (int*)carve((size_t)NPOS * 4);
  int*      meta   = (int*)carve(256);

  k_sample<<<NB, 64, 0, stream>>>(ids, seq, dm, tfp, tbu, meta, rowids);
  k_bucket<<<N_POI, 256, 0, stream>>>(dm, tfp, bucket, rbuf);
  k_rows<<<dim3(16, NB), 256, 0, stream>>>(rbuf, poi, y1t);
  k_layer<<<dim3(32, KC, NPAIR), 256, 0, stream>>>(bucket, tbu, y1t, part);
  k_reduce<<<dim3(64, NPAIR), 256, 0, stream>>>(part, rbuf, poi, table, y2t);
  k_layer2<<<dim3(16, KC2), 256, 0, stream>>>(bucket, tbu, y2t, rowids, part2);
  k_gather<<<dim3(NROWS, 16), 256, 0, stream>>>(seq, meta, table, poi, part2, rbuf,
                                                (float*)d_out);
}